// Round 1
// baseline (409.572 us; speedup 1.0000x reference)
//
#include <hip/hip_runtime.h>

#define NQ    14
#define NL    4
#define BATCH 2048
#define DIM   16384
#define BLK   1024
// padded LDS layout: float index k stored at k + (k>>5)  (breaks pow2 bank strides)
#define LSZ   (DIM + (DIM >> 5))

__device__ __forceinline__ int laddr(int k) { return k + (k >> 5); }

// Apply RX(c,s) on the register sub-index bit `stride` of a 16-amp register tile.
__device__ __forceinline__ void rx_regs16(float vr[16], float vi[16], float c, float s, int stride) {
#pragma unroll
  for (int a0 = 0; a0 < 16; ++a0) {
    if (!(a0 & stride)) {
      const int a1 = a0 | stride;
      const float r0 = vr[a0], i0 = vi[a0], r1 = vr[a1], i1 = vi[a1];
      vr[a0] = fmaf(c, r0,  s * i1);
      vi[a0] = fmaf(c, i0, -s * r1);
      vr[a1] = fmaf(c, r1,  s * i0);
      vi[a1] = fmaf(c, i1, -s * r0);
    }
  }
}

__global__ __launch_bounds__(BLK) void qsim_kernel(const float* __restrict__ x,
                                                   const float* __restrict__ params,
                                                   float* __restrict__ out) {
  __shared__ float sre[LSZ];
  __shared__ float sim_[LSZ];
  __shared__ float exc[NQ], exs[NQ];        // embedding cos/sin(x/2)
  __shared__ float gc[NL * NQ], gs[NL * NQ];// gate cos/sin(theta/2)

  const int b = blockIdx.x;
  const int t = threadIdx.x;

  if (t < NQ)      { const float xv = x[b * NQ + t]; exc[t] = cosf(0.5f * xv); exs[t] = sinf(0.5f * xv); }
  if (t < NL * NQ) { const float th = 0.5f * params[t]; gc[t] = cosf(th); gs[t] = sinf(th); }
  __syncthreads();

  // ---- RX angle embedding: amp(k) = (-i)^popc(k) * prod_q (bit_q(k) ? sin : cos)
  // qubit q sits at index bit position (13-q); thread owns k = t | (s2<<10)
  {
    float pb = 1.0f;
#pragma unroll
    for (int p = 0; p < 10; ++p) {
      const int q = 13 - p;
      pb *= ((t >> p) & 1) ? exs[q] : exc[q];
    }
    const int pct = __popc(t);
#pragma unroll
    for (int s2 = 0; s2 < 16; ++s2) {
      const int k = t | (s2 << 10);
      float f = pb;
#pragma unroll
      for (int j = 0; j < 4; ++j) {
        const int q = 3 - j;
        f *= ((s2 >> j) & 1) ? exs[q] : exc[q];
      }
      const int pc = (pct + __popc(s2)) & 3;
      const float rv = (pc == 0) ? f : ((pc == 2) ? -f : 0.0f);
      const float iv = (pc == 1) ? -f : ((pc == 3) ? f : 0.0f);
      const int a = laddr(k);
      sre[a] = rv; sim_[a] = iv;
    }
  }
  __syncthreads();

  for (int layer = 0; layer < NL; ++layer) {
    const float* lc = gc + layer * NQ;
    const float* ls = gs + layer * NQ;

    // Pass A: index bits 10..13 (qubits 3..0)
    {
      float vr[16], vi[16];
#pragma unroll
      for (int s2 = 0; s2 < 16; ++s2) { const int a = laddr(t | (s2 << 10)); vr[s2] = sre[a]; vi[s2] = sim_[a]; }
#pragma unroll
      for (int j = 0; j < 4; ++j) rx_regs16(vr, vi, lc[3 - j], ls[3 - j], 1 << j);
#pragma unroll
      for (int s2 = 0; s2 < 16; ++s2) { const int a = laddr(t | (s2 << 10)); sre[a] = vr[s2]; sim_[a] = vi[s2]; }
    }
    __syncthreads();

    // Pass B: index bits 6..9 (qubits 7..4)
    {
      const int base = (t & 63) | ((t >> 6) << 10);
      float vr[16], vi[16];
#pragma unroll
      for (int s2 = 0; s2 < 16; ++s2) { const int a = laddr(base | (s2 << 6)); vr[s2] = sre[a]; vi[s2] = sim_[a]; }
#pragma unroll
      for (int j = 0; j < 4; ++j) rx_regs16(vr, vi, lc[7 - j], ls[7 - j], 1 << j);
#pragma unroll
      for (int s2 = 0; s2 < 16; ++s2) { const int a = laddr(base | (s2 << 6)); sre[a] = vr[s2]; sim_[a] = vi[s2]; }
    }
    __syncthreads();

    // Pass C: index bits 2..5 (qubits 11..8)
    {
      const int base = (t & 3) | ((t >> 2) << 6);
      float vr[16], vi[16];
#pragma unroll
      for (int s2 = 0; s2 < 16; ++s2) { const int a = laddr(base | (s2 << 2)); vr[s2] = sre[a]; vi[s2] = sim_[a]; }
#pragma unroll
      for (int j = 0; j < 4; ++j) rx_regs16(vr, vi, lc[11 - j], ls[11 - j], 1 << j);
#pragma unroll
      for (int s2 = 0; s2 < 16; ++s2) { const int a = laddr(base | (s2 << 2)); sre[a] = vr[s2]; sim_[a] = vi[s2]; }
    }
    __syncthreads();

    // Pass D: index bits 0..1 (qubits 13,12), 4 quads per thread
    {
      const float c13 = lc[13], s13 = ls[13], c12 = lc[12], s12 = ls[12];
#pragma unroll
      for (int i = 0; i < 4; ++i) {
        const int base = (t + i * BLK) << 2;
        float vr[4], vi[4];
#pragma unroll
        for (int s2 = 0; s2 < 4; ++s2) { const int a = laddr(base | s2); vr[s2] = sre[a]; vi[s2] = sim_[a]; }
        // qubit 13 (bit 0)
#pragma unroll
        for (int a0 = 0; a0 < 4; a0 += 2) {
          const float r0 = vr[a0], i0v = vi[a0], r1 = vr[a0 + 1], i1v = vi[a0 + 1];
          vr[a0]     = fmaf(c13, r0,   s13 * i1v);
          vi[a0]     = fmaf(c13, i0v, -s13 * r1);
          vr[a0 + 1] = fmaf(c13, r1,   s13 * i0v);
          vi[a0 + 1] = fmaf(c13, i1v, -s13 * r0);
        }
        // qubit 12 (bit 1)
#pragma unroll
        for (int a0 = 0; a0 < 2; ++a0) {
          const int a1 = a0 + 2;
          const float r0 = vr[a0], i0v = vi[a0], r1 = vr[a1], i1v = vi[a1];
          vr[a0] = fmaf(c12, r0,   s12 * i1v);
          vi[a0] = fmaf(c12, i0v, -s12 * r1);
          vr[a1] = fmaf(c12, r1,   s12 * i0v);
          vi[a1] = fmaf(c12, i1v, -s12 * r0);
        }
#pragma unroll
        for (int s2 = 0; s2 < 4; ++s2) { const int a = laddr(base | s2); sre[a] = vr[s2]; sim_[a] = vi[s2]; }
      }
    }
    __syncthreads();

    // CNOT ring (14 CNOTs) == one GF(2)-linear basis permutation, done in ONE pass:
    //   new[P(k)] = old[k],  P(k) = (y & 0x1FFF) | ((y0 ^ b0)<<13),  y = suffix-xor(k)
    {
      float vr[16], vi[16];
#pragma unroll
      for (int s2 = 0; s2 < 16; ++s2) { const int a = laddr(t | (s2 << 10)); vr[s2] = sre[a]; vi[s2] = sim_[a]; }
      __syncthreads();
#pragma unroll
      for (int s2 = 0; s2 < 16; ++s2) {
        const int k = t | (s2 << 10);
        int y = k; y ^= y >> 1; y ^= y >> 2; y ^= y >> 4; y ^= y >> 8;
        const int j = (y & 0x1FFF) | (((y ^ (k >> 13)) & 1) << 13);
        const int a = laddr(j);
        sre[a] = vr[s2]; sim_[a] = vi[s2];
      }
    }
    __syncthreads();
  }

  // ---- probs -> <Z_q> = tot - 2 * sum_{bit_q=1} p
  {
    float tot = 0.0f;
    float acc[NQ];
#pragma unroll
    for (int q = 0; q < NQ; ++q) acc[q] = 0.0f;
#pragma unroll
    for (int s2 = 0; s2 < 16; ++s2) {
      const int k = t | (s2 << 10);
      const int a = laddr(k);
      const float rr = sre[a], ii = sim_[a];
      const float p = rr * rr + ii * ii;
      tot += p;
#pragma unroll
      for (int q = 0; q < NQ; ++q)
        if ((k >> (13 - q)) & 1) acc[q] += p;
    }
#pragma unroll
    for (int off = 32; off > 0; off >>= 1) {
      tot += __shfl_down(tot, off, 64);
#pragma unroll
      for (int q = 0; q < NQ; ++q) acc[q] += __shfl_down(acc[q], off, 64);
    }
    __syncthreads();  // all LDS reads done before scratch reuse
    const int wave = t >> 6, lane = t & 63;
    if (lane == 0) {
#pragma unroll
      for (int q = 0; q < NQ; ++q) sre[wave * 16 + q] = acc[q];
      sre[wave * 16 + 14] = tot;
    }
    __syncthreads();
    if (t < NQ) {
      float sq = 0.0f, tt = 0.0f;
#pragma unroll
      for (int w = 0; w < 16; ++w) { sq += sre[w * 16 + t]; tt += sre[w * 16 + 14]; }
      out[b * NQ + t] = tt - 2.0f * sq;
    }
  }
}

extern "C" void kernel_launch(void* const* d_in, const int* in_sizes, int n_in,
                              void* d_out, int out_size, void* d_ws, size_t ws_size,
                              hipStream_t stream) {
  const float* x      = (const float*)d_in[0];
  const float* params = (const float*)d_in[1];
  float* out          = (float*)d_out;
  qsim_kernel<<<BATCH, BLK, 0, stream>>>(x, params, out);
}

// Round 2
// 387.233 us; speedup vs baseline: 1.0577x; 1.0577x over previous
//
#include <hip/hip_runtime.h>

#define NQ    14
#define NL    4
#define BATCH 2048
#define DIM   16384
#define BLK   1024
#define MASK14 0x3FFF

// 16B-chunk XOR swizzle: same per-instr bank histogram as the optimal stride-1
// b128 pattern for both our read (per-thread contiguous) and write patterns.
__device__ __forceinline__ int csw(int c)  { return c ^ ((c >> 4) & 0xF); }
__device__ __forceinline__ int csw2(int a) { return (csw(a >> 1) << 1) | (a & 1); }
__device__ __forceinline__ int rol14(int a, int r) { return ((a << r) | (a >> (14 - r))) & MASK14; }

// RX pair-rotation on register-tile bit `b`: v' = c*v - i*s*v_partner (symmetric).
__device__ __forceinline__ void rot_bit(float vr[16], float vi[16], int b, float c, float s) {
#pragma unroll
  for (int j = 0; j < 16; ++j) {
    if (!(j & (1 << b))) {
      const int j1 = j | (1 << b);
      const float r0 = vr[j], i0 = vi[j], r1 = vr[j1], i1 = vi[j1];
      vr[j]  = fmaf(c, r0,  s * i1);
      vi[j]  = fmaf(c, i0, -s * r1);
      vr[j1] = fmaf(c, r1,  s * i0);
      vi[j1] = fmaf(c, i1, -s * r0);
    }
  }
}

__global__ __launch_bounds__(BLK, 4) void qsim_kernel(const float* __restrict__ x,
                                                      const float* __restrict__ params,
                                                      float* __restrict__ out) {
  __shared__ float4 lds4[DIM / 2];            // 8192 chunks = 128 KB, complex-interleaved
  __shared__ float exc[NQ], exs[NQ];          // embedding cos/sin(x/2)
  __shared__ float gc[NL * NQ], gs[NL * NQ];  // gate cos/sin(theta/2)
  __shared__ float red[16][16];               // cross-wave reduction staging

  float2* lds2 = reinterpret_cast<float2*>(lds4);

  const int b = blockIdx.x;
  const int t = threadIdx.x;

  if (t < NQ)      { const float xv = x[b * NQ + t]; exc[t] = cosf(0.5f * xv); exs[t] = sinf(0.5f * xv); }
  if (t < NL * NQ) { const float th = 0.5f * params[t]; gc[t] = cosf(th); gs[t] = sinf(th); }
  __syncthreads();

  float vr[16], vi[16];

  // ---- RX angle embedding directly into registers (layout r=0: thread owns a=k in [16t,16t+16))
  // k bit p <-> qubit 13-p;  amp(k) = (-i)^popc(k) * prod_p (bit_p ? sin : cos)
  {
    float pb = 1.0f;
#pragma unroll
    for (int p = 0; p < 10; ++p) pb *= ((t >> p) & 1) ? exs[9 - p] : exc[9 - p];
    const int pct = __popc(t);
#pragma unroll
    for (int j = 0; j < 16; ++j) {
      float f = pb;
#pragma unroll
      for (int bb = 0; bb < 4; ++bb) f *= ((j >> bb) & 1) ? exs[13 - bb] : exc[13 - bb];
      const int pc = (pct + __popc(j)) & 3;
      vr[j] = (pc == 0) ? f : ((pc == 2) ? -f : 0.0f);
      vi[j] = (pc == 1) ? -f : ((pc == 3) ? f : 0.0f);
    }
  }

  for (int layer = 0; layer < NL; ++layer) {
    const float* lc = gc + layer * NQ;
    const float* ls = gs + layer * NQ;

    // ---- pass 1 (layout r=0): a-bit b = k-bit b = qubit 13-b; rotate qubits 13,12,11,10
    if (layer > 0) {
#pragma unroll
      for (int i = 0; i < 8; ++i) {
        const float4 f = lds4[csw(8 * t + i)];
        vr[2 * i] = f.x; vi[2 * i] = f.y; vr[2 * i + 1] = f.z; vi[2 * i + 1] = f.w;
      }
    }
#pragma unroll
    for (int bb = 0; bb < 4; ++bb) rot_bit(vr, vi, bb, lc[13 - bb], ls[13 - bb]);
    if (layer > 0) __syncthreads();           // all reads done before rewriting LDS
    // write layout advanced by 3: a' = ror14(a,3) -> amps (j, j+8) contiguous
#pragma unroll
    for (int j7 = 0; j7 < 8; ++j7)
      lds4[csw(t + (j7 << 10))] = make_float4(vr[j7], vi[j7], vr[j7 + 8], vi[j7 + 8]);
    __syncthreads();

    // ---- passes 2..4: window = k bits {3p-3 .. 3p}; rotate 3 new qubits each
#pragma unroll
    for (int p = 2; p <= 4; ++p) {
#pragma unroll
      for (int i = 0; i < 8; ++i) {
        const float4 f = lds4[csw(8 * t + i)];
        vr[2 * i] = f.x; vi[2 * i] = f.y; vr[2 * i + 1] = f.z; vi[2 * i + 1] = f.w;
      }
      const int qbase = 13 - 3 * (p - 1);     // p=2:10, p=3:7, p=4:4
#pragma unroll
      for (int bb = 1; bb < 4; ++bb) rot_bit(vr, vi, bb, lc[qbase - bb], ls[qbase - bb]);
      __syncthreads();
#pragma unroll
      for (int j7 = 0; j7 < 8; ++j7)
        lds4[csw(t + (j7 << 10))] = make_float4(vr[j7], vi[j7], vr[j7 + 8], vi[j7 + 8]);
      __syncthreads();
    }

    // ---- pass 5 (layout r=12): a-bit 1 = k-bit 13 = qubit 0; rotate it
#pragma unroll
    for (int i = 0; i < 8; ++i) {
      const float4 f = lds4[csw(8 * t + i)];
      vr[2 * i] = f.x; vi[2 * i] = f.y; vr[2 * i + 1] = f.z; vi[2 * i + 1] = f.w;
    }
    rot_bit(vr, vi, 1, lc[0], ls[0]);
    __syncthreads();

    if (layer < NL - 1) {
      // CNOT ring folded into the write: new[C(k)] = old[k], back to layout r=0
#pragma unroll
      for (int j = 0; j < 16; ++j) {
        const int a = 16 * t + j;
        const int k = rol14(a, 12);
        int y = k; y ^= y >> 1; y ^= y >> 2; y ^= y >> 4; y ^= y >> 8;
        const int a2 = (y & 0x1FFF) | (((y ^ (k >> 13)) & 1) << 13);
        lds2[csw2(a2)] = make_float2(vr[j], vi[j]);
      }
      __syncthreads();
    } else {
      // ---- final layer: fold last CNOT + measurement (no store of the state)
      float tot = 0.0f, acc[NQ];
#pragma unroll
      for (int q = 0; q < NQ; ++q) acc[q] = 0.0f;
#pragma unroll
      for (int j = 0; j < 16; ++j) {
        const int a = 16 * t + j;
        const int k = rol14(a, 12);
        int y = k; y ^= y >> 1; y ^= y >> 2; y ^= y >> 4; y ^= y >> 8;
        const int jf = (y & 0x1FFF) | (((y ^ (k >> 13)) & 1) << 13);
        const float p = vr[j] * vr[j] + vi[j] * vi[j];
        tot += p;
#pragma unroll
        for (int q = 0; q < NQ; ++q)
          if ((jf >> (13 - q)) & 1) acc[q] += p;
      }
#pragma unroll
      for (int off = 32; off > 0; off >>= 1) {
        tot += __shfl_down(tot, off, 64);
#pragma unroll
        for (int q = 0; q < NQ; ++q) acc[q] += __shfl_down(acc[q], off, 64);
      }
      const int wave = t >> 6, lane = t & 63;
      if (lane == 0) {
#pragma unroll
        for (int q = 0; q < NQ; ++q) red[wave][q] = acc[q];
        red[wave][14] = tot;
      }
      __syncthreads();
      if (t < NQ) {
        float sq = 0.0f, tt = 0.0f;
#pragma unroll
        for (int w = 0; w < 16; ++w) { sq += red[w][t]; tt += red[w][14]; }
        out[b * NQ + t] = tt - 2.0f * sq;
      }
    }
  }
}

extern "C" void kernel_launch(void* const* d_in, const int* in_sizes, int n_in,
                              void* d_out, int out_size, void* d_ws, size_t ws_size,
                              hipStream_t stream) {
  const float* x      = (const float*)d_in[0];
  const float* params = (const float*)d_in[1];
  float* out          = (float*)d_out;
  qsim_kernel<<<BATCH, BLK, 0, stream>>>(x, params, out);
}

// Round 3
// 323.347 us; speedup vs baseline: 1.2667x; 1.1976x over previous
//
#include <hip/hip_runtime.h>

#define NQ     14
#define NL     4
#define BATCH  2048
#define DIM    16384
#define BLK    512
#define MASK14 0x3FFF
#define NCH    (DIM / 2)          // 8192 logical float4 chunks (2 amps each)
#define PCH    (NCH + NCH / 16)   // 8704 physical chunks: +1 pad chunk per 16 (bank spread)

using f2 = __attribute__((ext_vector_type(2))) float;

__device__ __forceinline__ f2 swapf2(f2 v) { return __builtin_shufflevector(v, v, 1, 0); }

// RX on register bit B of a 32-amp (f2) tile, packed-FP32 form:
//   new0 = C*a0 + S*swap(a1), new1 = C*a1 + S*swap(a0),  C=(c,c), S=(s,-s)
template <int B>
__device__ __forceinline__ void rot_bit(f2 v[32], float c, float s) {
  const f2 C = {c, c};
  const f2 S = {s, -s};
#pragma unroll
  for (int j = 0; j < 32; ++j) {
    if (!(j & B)) {
      const int j1 = j | B;
      const f2 a0 = v[j], a1 = v[j1];
      v[j]  = __builtin_elementwise_fma(C, a0, S * swapf2(a1));
      v[j1] = __builtin_elementwise_fma(C, a1, S * swapf2(a0));
    }
  }
}

__global__ __launch_bounds__(BLK, 2) void qsim_kernel(const float* __restrict__ x,
                                                      const float* __restrict__ params,
                                                      float* __restrict__ out) {
  __shared__ float4 lds4[PCH];                // 139264 B state, pad-swizzled
  __shared__ float exc[NQ], exs[NQ];          // embedding cos/sin(x/2)
  __shared__ float gc[NL * NQ], gs[NL * NQ];  // gate cos/sin(theta/2)
  __shared__ float red[8][16];                // cross-wave reduction staging
  f2* lds2 = reinterpret_cast<f2*>(lds4);

  const int b = blockIdx.x;
  const int t = threadIdx.x;

  if (t < NQ)      { const float xv = x[b * NQ + t]; exc[t] = cosf(0.5f * xv); exs[t] = sinf(0.5f * xv); }
  if (t < NL * NQ) { const float th = 0.5f * params[t]; gc[t] = cosf(th); gs[t] = sinf(th); }
  __syncthreads();

  f2 v[32];

  // ---- RX angle embedding straight into registers (layout L0: amp k = 32t + j)
  // k bit p <-> qubit 13-p; amp(k) = (-i)^popc(k) * prod_p (bit_p ? sin : cos)
  {
    float pb = 1.0f;
#pragma unroll
    for (int pt = 0; pt < 9; ++pt) pb *= ((t >> pt) & 1) ? exs[8 - pt] : exc[8 - pt];
    const int pct = __popc(t);
#pragma unroll
    for (int j = 0; j < 32; ++j) {
      float f = pb;
#pragma unroll
      for (int bb = 0; bb < 5; ++bb) f *= ((j >> bb) & 1) ? exs[13 - bb] : exc[13 - bb];
      const int pc = (pct + __popc(j)) & 3;
      f2 av;
      av.x = (pc == 0) ? f : ((pc == 2) ? -f : 0.0f);
      av.y = (pc == 1) ? -f : ((pc == 3) ? f : 0.0f);
      v[j] = av;
    }
  }

  // read base: logical chunks 16t..16t+15 live at physical 17t..17t+15 (immediate offsets)
  const float4* rp = lds4 + 17 * t;
  // write base: amp m of thread t -> logical addr a' = t | (m<<9); physical f2-slot
  //   = [2*((t>>1)+(t>>5)) + (t&1)] + m*544  (m<16 via wp0, m>=16 via wp1; 16-bit ds offsets)
  f2* wp0 = lds2 + (2 * ((t >> 1) + (t >> 5)) + (t & 1));
  f2* wp1 = wp0 + 16 * 544;

  for (int layer = 0; layer < NL; ++layer) {
    const float* lc = gc + layer * NQ;
    const float* ls = gs + layer * NQ;

    // ---- pass 1 (layout L0): reg bits 0..4 = qubits 13..9
    if (layer > 0) {
#pragma unroll
      for (int i = 0; i < 16; ++i) {
        const float4 f = rp[i];
        f2 lo; lo.x = f.x; lo.y = f.y;
        f2 hi; hi.x = f.z; hi.y = f.w;
        v[2 * i] = lo; v[2 * i + 1] = hi;
      }
    }
    rot_bit<1>(v, lc[13], ls[13]);
    rot_bit<2>(v, lc[12], ls[12]);
    rot_bit<4>(v, lc[11], ls[11]);
    rot_bit<8>(v, lc[10], ls[10]);
    rot_bit<16>(v, lc[9], ls[9]);
    __syncthreads();                       // WAR: all reads done before rewrite
#pragma unroll
    for (int j = 0; j < 16; ++j) wp0[j * 544] = v[j];
#pragma unroll
    for (int j = 0; j < 16; ++j) wp1[j * 544] = v[j + 16];
    __syncthreads();

    // ---- pass 2 (layout L9): reg bits 0..4 = qubits 8..4
#pragma unroll
    for (int i = 0; i < 16; ++i) {
      const float4 f = rp[i];
      f2 lo; lo.x = f.x; lo.y = f.y;
      f2 hi; hi.x = f.z; hi.y = f.w;
      v[2 * i] = lo; v[2 * i + 1] = hi;
    }
    rot_bit<1>(v, lc[8], ls[8]);
    rot_bit<2>(v, lc[7], ls[7]);
    rot_bit<4>(v, lc[6], ls[6]);
    rot_bit<8>(v, lc[5], ls[5]);
    rot_bit<16>(v, lc[4], ls[4]);
    __syncthreads();
#pragma unroll
    for (int j = 0; j < 16; ++j) wp0[j * 544] = v[j];
#pragma unroll
    for (int j = 0; j < 16; ++j) wp1[j * 544] = v[j + 16];
    __syncthreads();

    // ---- pass 3 (layout L4): reg bits 0..3 = qubits 3..0 (bit 4 = qubit 13, done in pass 1)
#pragma unroll
    for (int i = 0; i < 16; ++i) {
      const float4 f = rp[i];
      f2 lo; lo.x = f.x; lo.y = f.y;
      f2 hi; hi.x = f.z; hi.y = f.w;
      v[2 * i] = lo; v[2 * i + 1] = hi;
    }
    rot_bit<1>(v, lc[3], ls[3]);
    rot_bit<2>(v, lc[2], ls[2]);
    rot_bit<4>(v, lc[1], ls[1]);
    rot_bit<8>(v, lc[0], ls[0]);

    if (layer < NL - 1) {
      // CNOT ring folded into one scatter back to layout L0: new[C(k)] = old[k]
      __syncthreads();
#pragma unroll
      for (int j = 0; j < 32; ++j) {
        const int a = 32 * t + j;                       // L4 address
        const int k = ((a >> 4) | (a << 10)) & MASK14;  // ror14(a,4)
        int y = k; y ^= y >> 1; y ^= y >> 2; y ^= y >> 4; y ^= y >> 8;
        const int a2 = (y & 0x1FFF) | (((y ^ (k >> 13)) & 1) << 13);
        lds2[a2 + 2 * (a2 >> 5)] = v[j];                // pad-swizzled slot
      }
      __syncthreads();
    }
  }

  // ---- final layer: fold last CNOT + measurement straight from registers
  {
    float tot = 0.0f, acc[NQ];
#pragma unroll
    for (int q = 0; q < NQ; ++q) acc[q] = 0.0f;
#pragma unroll
    for (int j = 0; j < 32; ++j) {
      const int a = 32 * t + j;
      const int k = ((a >> 4) | (a << 10)) & MASK14;
      int y = k; y ^= y >> 1; y ^= y >> 2; y ^= y >> 4; y ^= y >> 8;
      const int jf = (y & 0x1FFF) | (((y ^ (k >> 13)) & 1) << 13);
      const f2 av = v[j];
      const float p = av.x * av.x + av.y * av.y;
      tot += p;
#pragma unroll
      for (int q = 0; q < NQ; ++q)
        if ((jf >> (13 - q)) & 1) acc[q] += p;
    }
#pragma unroll
    for (int off = 32; off > 0; off >>= 1) {
      tot += __shfl_down(tot, off, 64);
#pragma unroll
      for (int q = 0; q < NQ; ++q) acc[q] += __shfl_down(acc[q], off, 64);
    }
    const int wave = t >> 6, lane = t & 63;
    if (lane == 0) {
#pragma unroll
      for (int q = 0; q < NQ; ++q) red[wave][q] = acc[q];
      red[wave][14] = tot;
    }
    __syncthreads();
    if (t < NQ) {
      float sq = 0.0f, tt = 0.0f;
#pragma unroll
      for (int w = 0; w < 8; ++w) { sq += red[w][t]; tt += red[w][14]; }
      out[b * NQ + t] = tt - 2.0f * sq;
    }
  }
}

extern "C" void kernel_launch(void* const* d_in, const int* in_sizes, int n_in,
                              void* d_out, int out_size, void* d_ws, size_t ws_size,
                              hipStream_t stream) {
  const float* x      = (const float*)d_in[0];
  const float* params = (const float*)d_in[1];
  float* out          = (float*)d_out;
  qsim_kernel<<<BATCH, BLK, 0, stream>>>(x, params, out);
}

// Round 4
// 251.416 us; speedup vs baseline: 1.6291x; 1.2861x over previous
//
#include <hip/hip_runtime.h>

#define NQ     14
#define NL     4
#define BATCH  2048
#define DIM    16384
#define BLK    512

using f2 = __attribute__((ext_vector_type(2))) float;

__device__ __forceinline__ f2 swapf2(f2 v) { return __builtin_shufflevector(v, v, 1, 0); }

// RX on register-index bit B of a 32-amp (f2) tile, packed-FP32 form.
template <int B>
__device__ __forceinline__ void rot_bit(f2* v, float c, float s) {
  const f2 C = {c, c};
  const f2 S = {s, -s};
#pragma unroll
  for (int j = 0; j < 32; ++j) {
    if (!(j & B)) {
      const int j1 = j | B;
      const f2 a0 = v[j], a1 = v[j1];
      v[j]  = __builtin_elementwise_fma(C, a0, S * swapf2(a1));
      v[j1] = __builtin_elementwise_fma(C, a1, S * swapf2(a0));
    }
  }
}

// CNOT-ring basis map (linear over GF(2)): jf(k) = (y & 0x1FFF) | ((y0^k13)<<13), y=suffix-xor(k)
__device__ __forceinline__ int cnot_map(int k) {
  int y = k; y ^= y >> 1; y ^= y >> 2; y ^= y >> 4; y ^= y >> 8;
  return (y & 0x1FFF) | (((y ^ (k >> 13)) & 1) << 13);
}
// compile-time images of amp-bits 9..13 under the CNOT map
__host__ __device__ constexpr int G_of(int j) {
  int g = 0;
  if (j & 1)  g ^= 0x23FF;  // M(e9)
  if (j & 2)  g ^= 0x27FF;  // M(e10)
  if (j & 4)  g ^= 0x2FFF;  // M(e11)
  if (j & 8)  g ^= 0x3FFF;  // M(e12)
  if (j & 16) g ^= 0x1FFF;  // M(e13)
  return g;
}

__global__ __launch_bounds__(BLK, 2) void qsim_kernel(const float* __restrict__ x,
                                                      const float* __restrict__ params,
                                                      float* __restrict__ out) {
  // fixed layout: logical chunk c (amps 2c,2c+1) at physical chunk c + (c>>4)
  __shared__ float4 lds4[DIM / 2 + DIM / 32];  // 8704 chunks = 139264 B
  __shared__ float exc[NQ], exs[NQ];
  __shared__ float gc[NL * NQ], gs[NL * NQ];
  __shared__ float red[8][NQ];
  f2* lds2 = reinterpret_cast<f2*>(lds4);      // f2 slot s -> phys s + 2*(s>>5)

  const int b = blockIdx.x;
  const int t = threadIdx.x;

  if (t < NQ)      { const float xv = x[b * NQ + t]; exc[t] = cosf(0.5f * xv); exs[t] = sinf(0.5f * xv); }
  if (t < NL * NQ) { const float th = 0.5f * params[t]; gc[t] = cosf(th); gs[t] = sinf(th); }
  __syncthreads();

  float4 tile[16];
  f2* v = reinterpret_cast<f2*>(tile);

  // ---- embedding in pass-A ownership: amp a = (t<<5)|j ; a-bit p <-> qubit 13-p
  {
    float pb = 1.0f;
#pragma unroll
    for (int pt = 0; pt < 9; ++pt) pb *= ((t >> pt) & 1) ? exs[8 - pt] : exc[8 - pt];
    const int pct = __popc(t);
#pragma unroll
    for (int j = 0; j < 32; ++j) {
      float f = pb;
#pragma unroll
      for (int bb = 0; bb < 5; ++bb) f *= ((j >> bb) & 1) ? exs[13 - bb] : exc[13 - bb];
      const int pc = (pct + __popc(j)) & 3;
      f2 av;
      av.x = (pc == 0) ? f : ((pc == 2) ? -f : 0.0f);
      av.y = (pc == 1) ? -f : ((pc == 3) ? f : 0.0f);
      v[j] = av;
    }
  }

  const int baseA = 17 * t;                                      // phys chunk of c=16t
  const int baseB = (t & 15) + ((t >> 4) << 8) + ((t >> 4) << 4);// phys chunk, offsets 17*jj
  const int baseC = t + 2 * (t >> 5);                            // phys f2 slot, offsets 544*j
  const int jft   = cnot_map(t);                                 // t occupies amp bits 0..8

#pragma unroll
  for (int layer = 0; layer < NL; ++layer) {
    const float* lc = gc + layer * NQ;
    const float* ls = gs + layer * NQ;

    // ---- pass A: own amps a=(t<<5)|j ; rotate q13..q9 (reg bits 0..4). Self-owned slots.
    if (layer > 0) {
#pragma unroll
      for (int i = 0; i < 16; ++i) tile[i] = lds4[baseA + i];
    }
    rot_bit<1>(v, lc[13], ls[13]);
    rot_bit<2>(v, lc[12], ls[12]);
    rot_bit<4>(v, lc[11], ls[11]);
    rot_bit<8>(v, lc[10], ls[10]);
    rot_bit<16>(v, lc[9], ls[9]);
#pragma unroll
    for (int i = 0; i < 16; ++i) lds4[baseA + i] = tile[i];
    __syncthreads();

    // ---- pass B: free amp-bits {0,5,6,7,8}; rotate q8..q5 (reg bits 1..4)
#pragma unroll
    for (int jj = 0; jj < 16; ++jj) tile[jj] = lds4[baseB + 17 * jj];
    rot_bit<2>(v, lc[8], ls[8]);
    rot_bit<4>(v, lc[7], ls[7]);
    rot_bit<8>(v, lc[6], ls[6]);
    rot_bit<16>(v, lc[5], ls[5]);
#pragma unroll
    for (int jj = 0; jj < 16; ++jj) lds4[baseB + 17 * jj] = tile[jj];
    __syncthreads();

    // ---- pass C: own amps a = t | (j<<9); rotate q4..q0 (reg bits 0..4)
#pragma unroll
    for (int j = 0; j < 16; ++j) v[j] = lds2[baseC + 544 * j];
#pragma unroll
    for (int j = 16; j < 32; ++j) v[j] = lds2[(baseC + 16 * 544) + 544 * (j - 16)];
    rot_bit<1>(v, lc[4], ls[4]);
    rot_bit<2>(v, lc[3], ls[3]);
    rot_bit<4>(v, lc[2], ls[2]);
    rot_bit<8>(v, lc[1], ls[1]);
    rot_bit<16>(v, lc[0], ls[0]);

    if (layer < NL - 1) {
      // CNOT ring folded into the write-back: slot jf = jft ^ G[j] (constants)
      __syncthreads();  // WAR: all pass-C reads done
#pragma unroll
      for (int j = 0; j < 32; ++j) {
        const int s = jft ^ G_of(j);
        lds2[s + 2 * (s >> 5)] = v[j];
      }
      __syncthreads();
    }
  }

  // ---- measurement: bit_b(jf(a)) = bit_b(jft) ^ parity(j & m_b)  (GF(2)-linear CNOT)
  // => per-thread signed sums are Walsh coefficients of p[j]
  {
    float p[32];
#pragma unroll
    for (int j = 0; j < 32; ++j) p[j] = v[j].x * v[j].x + v[j].y * v[j].y;
    // 5-stage Walsh-Hadamard butterfly: p[m] <- sum_j (-1)^popc(j&m) p_j
#pragma unroll
    for (int st = 0; st < 5; ++st) {
      const int h = 1 << st;
#pragma unroll
      for (int j = 0; j < 32; ++j) {
        if (!(j & h)) {
          const float u = p[j], w = p[j | h];
          p[j] = u + w;
          p[j | h] = u - w;
        }
      }
    }
    float av[NQ];
    av[0] = ((jft >> 13) & 1) ? -p[15] : p[15];
    av[1] = ((jft >> 12) & 1) ? -p[24] : p[24];
    av[2] = ((jft >> 11) & 1) ? -p[28] : p[28];
    av[3] = ((jft >> 10) & 1) ? -p[30] : p[30];
#pragma unroll
    for (int q = 4; q < NQ; ++q) av[q] = ((jft >> (13 - q)) & 1) ? -p[31] : p[31];

#pragma unroll
    for (int off = 32; off > 0; off >>= 1)
#pragma unroll
      for (int q = 0; q < NQ; ++q) av[q] += __shfl_down(av[q], off, 64);

    __syncthreads();  // state reads done (scratch about to be reused conceptually)
    const int wave = t >> 6, lane = t & 63;
    if (lane == 0) {
#pragma unroll
      for (int q = 0; q < NQ; ++q) red[wave][q] = av[q];
    }
    __syncthreads();
    if (t < NQ) {
      float sq = 0.0f;
#pragma unroll
      for (int w = 0; w < 8; ++w) sq += red[w][t];
      out[b * NQ + t] = sq;
    }
  }
}

extern "C" void kernel_launch(void* const* d_in, const int* in_sizes, int n_in,
                              void* d_out, int out_size, void* d_ws, size_t ws_size,
                              hipStream_t stream) {
  const float* x      = (const float*)d_in[0];
  const float* params = (const float*)d_in[1];
  float* out          = (float*)d_out;
  qsim_kernel<<<BATCH, BLK, 0, stream>>>(x, params, out);
}